// Round 1
// baseline (36908.481 us; speedup 1.0000x reference)
//
#include <hip/hip_runtime.h>
#include <hip/hip_bf16.h>
#include <hip/hip_cooperative_groups.h>

namespace cg = cooperative_groups;

#define TT 1024
#define BB 128
#define II 256
#define HH 256

// ping-pong hidden state (static device memory: no workspace-size assumptions)
__device__ float g_h[2][BB][HH];

__device__ __forceinline__ float bf_hi(unsigned u) { return __uint_as_float(u & 0xffff0000u); }
__device__ __forceinline__ float bf_lo(unsigned u) { return __uint_as_float(u << 16); }

__device__ __forceinline__ unsigned pack2(float a, float b) {
    // lo half = a, hi half = b (RNE via HIP bf16 API)
    __hip_bfloat16 ha = __float2bfloat16(a);
    __hip_bfloat16 hb = __float2bfloat16(b);
    unsigned ua = *reinterpret_cast<unsigned short*>(&ha);
    unsigned ub = *reinterpret_cast<unsigned short*>(&hb);
    return ua | (ub << 16);
}

// Per-k inner step: 1 LDS b64 + 1 LDS b32 (weights, bf16-packed), 6 unpacks, 6 FMAs
#define STEPK(KB, HV, XV)                                                     \
    {                                                                         \
        uint2    a = wA[KB][jj];                                              \
        unsigned c = wB[KB][jj];                                              \
        aR += (HV) * bf_lo(a.x);  aZ += (HV) * bf_hi(a.x);                    \
        aN += (HV) * bf_lo(a.y);                                              \
        iR += (XV) * bf_hi(a.y);  iZ += (XV) * bf_lo(c);                      \
        iN += (XV) * bf_hi(c);                                                \
    }

__global__ void __launch_bounds__(256, 1) gru_fused(
    const float* __restrict__ x, const float* __restrict__ h0,
    const float* __restrict__ wihT, const float* __restrict__ whhT,
    const float* __restrict__ bias, float* __restrict__ out)
{
    // wA[k][jj] = {bf16 whhR, whhZ | whhN, wihR}; wB[k][jj] = {wihZ, wihN}
    __shared__ uint2    wA[256][16];   // 32 KB
    __shared__ unsigned wB[256][16];   // 16 KB

    const int wg   = blockIdx.x;             // 256 WGs
    const int jb   = wg & 15;                // 16 j-blocks of 16 columns
    const int bg   = wg >> 4;                // 16 b-groups of 8 rows
    const int tid  = threadIdx.x;
    const int jj   = tid & 15;
    const int j    = jb * 16 + jj;           // hidden column
    const int kq   = (tid >> 5) & 1;         // k-half (lane bit 5 -> shfl_xor 32)
    const int b_in = ((tid >> 4) & 1) | (((tid >> 6) & 3) << 1);
    const int b    = bg * 8 + b_in;          // batch row

    // Stage step-invariant weight slices into LDS once (bf16-packed).
    for (int s = tid; s < 256 * 16; s += 256) {
        const int k = s >> 4, q = s & 15;
        const int col = jb * 16 + q;
        const float whhR = whhT[k * 768 + col];
        const float whhZ = whhT[k * 768 + 256 + col];
        const float whhN = whhT[k * 768 + 512 + col];
        const float wihR = wihT[k * 768 + col];
        const float wihZ = wihT[k * 768 + 256 + col];
        const float wihN = wihT[k * 768 + 512 + col];
        wA[k][q] = make_uint2(pack2(whhR, whhZ), pack2(whhN, wihR));
        wB[k][q] = pack2(wihZ, wihN);
    }

    const float br = bias[j];
    const float bz = bias[HH + j];
    const float bn = bias[2 * HH + j];

    cg::grid_group grid = cg::this_grid();

    // Init hidden state from h0 (grid-strided; also orders LDS staging via sync)
    for (int s = wg * 256 + tid; s < BB * HH; s += 256 * 256)
        (&g_h[0][0][0])[s] = h0[s];
    grid.sync();

    for (int t = 0; t < TT; ++t) {
        const int cur = t & 1, nxt = cur ^ 1;
        const float4* __restrict__ hrow4 =
            reinterpret_cast<const float4*>(&g_h[cur][b][0]);
        const float4* __restrict__ xrow4 =
            reinterpret_cast<const float4*>(x + ((size_t)t * BB + b) * II);

        float aR = 0.f, aZ = 0.f, aN = 0.f;   // gh dots (r,z,n)
        float iR = 0.f, iZ = 0.f, iN = 0.f;   // gi dots (r,z,n)

        #pragma unroll 8
        for (int kk = 0; kk < 32; ++kk) {
            const int    k4 = kq * 32 + kk;    // float4 index into row
            const float4 hv = hrow4[k4];
            const float4 xv = xrow4[k4];
            const int    kb = k4 * 4;
            STEPK(kb + 0, hv.x, xv.x)
            STEPK(kb + 1, hv.y, xv.y)
            STEPK(kb + 2, hv.z, xv.z)
            STEPK(kb + 3, hv.w, xv.w)
        }

        // combine the two k-halves (partner lane differs in bit 5 -> same wave)
        aR += __shfl_xor(aR, 32); aZ += __shfl_xor(aZ, 32); aN += __shfl_xor(aN, 32);
        iR += __shfl_xor(iR, 32); iZ += __shfl_xor(iZ, 32); iN += __shfl_xor(iN, 32);

        const float r  = 1.f / (1.f + __expf(-(iR + br + aR)));
        const float z  = 1.f / (1.f + __expf(-(iZ + bz + aZ)));
        const float n  = tanhf(iN + bn + r * aN);   // note: bn NOT scaled by r
        const float hp = g_h[cur][b][j];
        const float hn = (1.f - z) * n + z * hp;

        if (kq == 0) {
            g_h[nxt][b][j] = hn;
            if (t == TT - 1) out[b * HH + j] = hn;
        }
        grid.sync();
    }
}

extern "C" void kernel_launch(void* const* d_in, const int* in_sizes, int n_in,
                              void* d_out, int out_size, void* d_ws, size_t ws_size,
                              hipStream_t stream) {
    const float* x    = (const float*)d_in[0];
    const float* h0   = (const float*)d_in[1];
    const float* wihT = (const float*)d_in[2];
    const float* whhT = (const float*)d_in[3];
    const float* bias = (const float*)d_in[4];
    float*       out  = (float*)d_out;

    void* args[] = { (void*)&x, (void*)&h0, (void*)&wihT, (void*)&whhT,
                     (void*)&bias, (void*)&out };
    hipLaunchCooperativeKernel((void*)gru_fused, dim3(256), dim3(256),
                               args, 0, stream);
}

// Round 2
// 2258.993 us; speedup vs baseline: 16.3385x; 16.3385x over previous
//
#include <hip/hip_runtime.h>
#include <hip/hip_fp16.h>

#define TT 1024
#define BB 128
#define II 256
#define HH 256
#define NG 768   // 3*H

// Static scratch (ws_size unknown): x in bf16, wih transposed bf16, gi fp32.
__device__ __align__(16) unsigned short g_xbf[(size_t)TT * BB * II];   // 67 MB
__device__ __align__(16) unsigned short g_wihB[NG * II];               // 384 KB, [n][k]
__device__ __align__(16) float          g_gi[(size_t)TT * BB * NG];    // 402 MB

typedef __attribute__((ext_vector_type(8))) short   bfrag;   // 8 bf16 = 4 VGPR
typedef __attribute__((ext_vector_type(4))) float   f32x4;
typedef __attribute__((ext_vector_type(2))) _Float16 h2t;

__device__ __forceinline__ unsigned short f2bf(float f) {
    unsigned u = __float_as_uint(f);
    return (unsigned short)((u + 0x7fffu + ((u >> 16) & 1u)) >> 16);   // RNE
}
__device__ __forceinline__ unsigned short f2h_bits(float f) {
    return (unsigned short)(__builtin_bit_cast(unsigned,
               __builtin_amdgcn_cvt_pkrtz(f, 0.f)) & 0xffffu);
}

// ---------------- phase 1a: x f32 -> bf16 ----------------
__global__ void cvt_x_kernel(const float* __restrict__ x) {
    const int n4 = TT * BB * II / 4;
    for (int i = blockIdx.x * blockDim.x + threadIdx.x; i < n4;
         i += gridDim.x * blockDim.x) {
        float4 v = reinterpret_cast<const float4*>(x)[i];
        ushort4 o;
        o.x = f2bf(v.x); o.y = f2bf(v.y); o.z = f2bf(v.z); o.w = f2bf(v.w);
        reinterpret_cast<ushort4*>(g_xbf)[i] = o;
    }
}

// ---------------- phase 1b: wihT [k][n] f32 -> wihB [n][k] bf16 ----------------
__global__ void cvt_wih_kernel(const float* __restrict__ wihT) {
    const int n = blockIdx.x;    // 0..767
    const int k = threadIdx.x;   // 0..255
    g_wihB[n * II + k] = f2bf(wihT[k * NG + n]);
}

// ---------------- phase 2: gi = x @ wihT  (MFMA bf16, fp32 out) ----------------
// M = TT*BB = 131072 (1024 tiles of 128), N = 768 (6 tiles of 128), K = 256.
__global__ void __launch_bounds__(256) gi_gemm_kernel() {
    __shared__ unsigned short Ab[128 * 32];   // A tile [m][k] bf16
    __shared__ unsigned short Bb[128 * 32];   // B tile [n][k] bf16 (from wihB)
    const int tid = threadIdx.x;
    const int mt = blockIdx.x / 6, nt = blockIdx.x % 6;
    const int m0 = mt * 128, n0 = nt * 128;
    const int l = tid & 63, w = tid >> 6;
    const int wr = w >> 1, wc = w & 1;           // 2x2 wave grid, 64x64 each
    const int srow = tid >> 2, scol = (tid & 3) * 8;

    f32x4 acc[4][4] = {};

    for (int ks = 0; ks < 8; ++ks) {
        const int k0 = ks * 32;
        __syncthreads();   // WAR: previous frag reads done before overwrite
        #pragma unroll
        for (int c = 0; c < 2; ++c) {
            const int row = c * 64 + srow;
            *reinterpret_cast<uint4*>(&Ab[row * 32 + scol]) =
                *reinterpret_cast<const uint4*>(&g_xbf[(size_t)(m0 + row) * II + k0 + scol]);
            *reinterpret_cast<uint4*>(&Bb[row * 32 + scol]) =
                *reinterpret_cast<const uint4*>(&g_wihB[(n0 + row) * II + k0 + scol]);
        }
        __syncthreads();
        bfrag af[4], bf[4];
        #pragma unroll
        for (int i = 0; i < 4; ++i) {
            af[i] = *reinterpret_cast<const bfrag*>(
                        &Ab[(wr * 64 + i * 16 + (l & 15)) * 32 + (l >> 4) * 8]);
            bf[i] = *reinterpret_cast<const bfrag*>(
                        &Bb[(wc * 64 + i * 16 + (l & 15)) * 32 + (l >> 4) * 8]);
        }
        #pragma unroll
        for (int mi = 0; mi < 4; ++mi)
            #pragma unroll
            for (int ni = 0; ni < 4; ++ni)
                acc[mi][ni] = __builtin_amdgcn_mfma_f32_16x16x32_bf16(
                                  af[mi], bf[ni], acc[mi][ni], 0, 0, 0);
    }
    // C/D layout (m89-verified): col = lane&15, row = (lane>>4)*4 + q
    #pragma unroll
    for (int mi = 0; mi < 4; ++mi) {
        const int grow = m0 + wr * 64 + mi * 16 + (l >> 4) * 4;
        #pragma unroll
        for (int ni = 0; ni < 4; ++ni) {
            const int gcol = n0 + wc * 64 + ni * 16 + (l & 15);
            #pragma unroll
            for (int q = 0; q < 4; ++q)
                g_gi[(size_t)(grow + q) * NG + gcol] = acc[mi][ni][q];
        }
    }
}

// ---------------- phase 3: recurrence, one WG per batch row ----------------
#if defined(__has_builtin)
#  if __has_builtin(__builtin_amdgcn_fdot2)
#    define USE_FDOT2 1
#  endif
#endif

__global__ void __launch_bounds__(256, 1) gru_rec_kernel(
    const float* __restrict__ h0, const float* __restrict__ whhT,
    const float* __restrict__ bias, float* __restrict__ out)
{
    __shared__ unsigned short hpk[HH];   // h as f16, rebroadcast each step
    const int b = blockIdx.x;
    const int j = threadIdx.x;           // output column 0..255
    const int lane = j & 63;

    // whh columns j (r), j+256 (z), j+512 (n) as packed f16x2 — in registers.
    unsigned wr_[128], wz_[128], wn_[128];
    #pragma unroll
    for (int p = 0; p < 128; ++p) {
        const float r0 = whhT[(2 * p) * NG + j];
        const float r1 = whhT[(2 * p + 1) * NG + j];
        const float z0 = whhT[(2 * p) * NG + 256 + j];
        const float z1 = whhT[(2 * p + 1) * NG + 256 + j];
        const float n0 = whhT[(2 * p) * NG + 512 + j];
        const float n1 = whhT[(2 * p + 1) * NG + 512 + j];
        wr_[p] = __builtin_bit_cast(unsigned, __builtin_amdgcn_cvt_pkrtz(r0, r1));
        wz_[p] = __builtin_bit_cast(unsigned, __builtin_amdgcn_cvt_pkrtz(z0, z1));
        wn_[p] = __builtin_bit_cast(unsigned, __builtin_amdgcn_cvt_pkrtz(n0, n1));
    }
    const float br = bias[j], bz = bias[256 + j], bn = bias[512 + j];

    float hprev = h0[b * HH + j];
    hpk[j] = f2h_bits(hprev);
    __syncthreads();

    const float* gib = g_gi + (size_t)b * NG + j;
    const unsigned* hp32 = reinterpret_cast<const unsigned*>(hpk);

    for (int t = 0; t < TT; ++t) {
        const float* gt = gib + (size_t)t * (BB * NG);
        const float giR = gt[0], giZ = gt[256], giN = gt[512];

        const unsigned ha = hp32[lane];        // pairs 0..63 (lane-distributed)
        const unsigned hb = hp32[lane + 64];   // pairs 64..127

        float aR0 = 0.f, aR1 = 0.f, aZ0 = 0.f, aZ1 = 0.f, aN0 = 0.f, aN1 = 0.f;

#if USE_FDOT2
        #define DOTP(P, SRC, LN)                                                   \
        {                                                                          \
            const unsigned hu = (unsigned)__builtin_amdgcn_readlane((int)(SRC), (LN)); \
            const h2t hh = __builtin_bit_cast(h2t, hu);                            \
            if (((P) & 1) == 0) {                                                  \
                aR0 = __builtin_amdgcn_fdot2(hh, __builtin_bit_cast(h2t, wr_[P]), aR0, false); \
                aZ0 = __builtin_amdgcn_fdot2(hh, __builtin_bit_cast(h2t, wz_[P]), aZ0, false); \
                aN0 = __builtin_amdgcn_fdot2(hh, __builtin_bit_cast(h2t, wn_[P]), aN0, false); \
            } else {                                                               \
                aR1 = __builtin_amdgcn_fdot2(hh, __builtin_bit_cast(h2t, wr_[P]), aR1, false); \
                aZ1 = __builtin_amdgcn_fdot2(hh, __builtin_bit_cast(h2t, wz_[P]), aZ1, false); \
                aN1 = __builtin_amdgcn_fdot2(hh, __builtin_bit_cast(h2t, wn_[P]), aN1, false); \
            }                                                                      \
        }
#else
        #define DOTP(P, SRC, LN)                                                   \
        {                                                                          \
            unsigned hu = (unsigned)__builtin_amdgcn_readlane((int)(SRC), (LN));   \
            const __half2 hh2 = *reinterpret_cast<const __half2*>(&hu);            \
            const float2 hf = __half22float2(hh2);                                 \
            unsigned wu;  __half2 wh2;  float2 wf;                                 \
            wu = wr_[P]; wh2 = *reinterpret_cast<const __half2*>(&wu);             \
            wf = __half22float2(wh2);                                              \
            if (((P) & 1) == 0) { aR0 += hf.x * wf.x; aR0 += hf.y * wf.y; }        \
            else                { aR1 += hf.x * wf.x; aR1 += hf.y * wf.y; }        \
            wu = wz_[P]; wh2 = *reinterpret_cast<const __half2*>(&wu);             \
            wf = __half22float2(wh2);                                              \
            if (((P) & 1) == 0) { aZ0 += hf.x * wf.x; aZ0 += hf.y * wf.y; }        \
            else                { aZ1 += hf.x * wf.x; aZ1 += hf.y * wf.y; }        \
            wu = wn_[P]; wh2 = *reinterpret_cast<const __half2*>(&wu);             \
            wf = __half22float2(wh2);                                              \
            if (((P) & 1) == 0) { aN0 += hf.x * wf.x; aN0 += hf.y * wf.y; }        \
            else                { aN1 += hf.x * wf.x; aN1 += hf.y * wf.y; }        \
        }
#endif
        #pragma unroll
        for (int p = 0; p < 64; ++p) DOTP(p, ha, p)
        #pragma unroll
        for (int p = 0; p < 64; ++p) DOTP(p + 64, hb, p)
        #undef DOTP

        const float accR = aR0 + aR1, accZ = aZ0 + aZ1, accN = aN0 + aN1;

        const float r = 1.f / (1.f + __expf(-(giR + br + accR)));
        const float z = 1.f / (1.f + __expf(-(giZ + bz + accZ)));
        float n;
        { const float e = __expf(2.f * (giN + bn + r * accN));  // tanh(x)
          n = 1.f - 2.f / (e + 1.f); }
        const float hn = (1.f - z) * n + z * hprev;
        hprev = hn;

        __syncthreads();                 // all waves done reading ha/hb
        hpk[j] = f2h_bits(hn);
        if (t == TT - 1) out[b * HH + j] = hn;
        __syncthreads();                 // h published for next step
    }
}

extern "C" void kernel_launch(void* const* d_in, const int* in_sizes, int n_in,
                              void* d_out, int out_size, void* d_ws, size_t ws_size,
                              hipStream_t stream) {
    const float* x    = (const float*)d_in[0];
    const float* h0   = (const float*)d_in[1];
    const float* wihT = (const float*)d_in[2];
    const float* whhT = (const float*)d_in[3];
    const float* bias = (const float*)d_in[4];
    float*       out  = (float*)d_out;

    cvt_x_kernel<<<2048, 256, 0, stream>>>(x);
    cvt_wih_kernel<<<NG, 256, 0, stream>>>(wihT);
    gi_gemm_kernel<<<1024 * 6, 256, 0, stream>>>();
    gru_rec_kernel<<<BB, 256, 0, stream>>>(h0, whhT, bias, out);
}

// Round 3
// 1743.090 us; speedup vs baseline: 21.1742x; 1.2960x over previous
//
#include <hip/hip_runtime.h>
#include <hip/hip_fp16.h>

#define TT 1024
#define BB 128
#define II 256
#define HH 256
#define NG 768   // 3*H

// Static scratch (ws_size unknown): x in bf16, wih transposed bf16, gi fp32.
__device__ __align__(16) unsigned short g_xbf[(size_t)TT * BB * II];   // 67 MB
__device__ __align__(16) unsigned short g_wihB[NG * II];               // 384 KB, [n][k]
__device__ __align__(16) float          g_gi[(size_t)TT * BB * NG];    // 402 MB

typedef __attribute__((ext_vector_type(8))) short   bfrag;   // 8 bf16 = 4 VGPR
typedef __attribute__((ext_vector_type(4))) float   f32x4;
typedef __attribute__((ext_vector_type(2))) _Float16 h2t;

__device__ __forceinline__ unsigned short f2bf(float f) {
    unsigned u = __float_as_uint(f);
    return (unsigned short)((u + 0x7fffu + ((u >> 16) & 1u)) >> 16);   // RNE
}
__device__ __forceinline__ unsigned short f2h_bits(float f) {
    return (unsigned short)(__builtin_bit_cast(unsigned,
               __builtin_amdgcn_cvt_pkrtz(f, 0.f)) & 0xffffu);
}
__device__ __forceinline__ unsigned pk2(float a, float b) {
    return __builtin_bit_cast(unsigned, __builtin_amdgcn_cvt_pkrtz(a, b));
}

// ---------------- phase 1a: x f32 -> bf16 ----------------
__global__ void cvt_x_kernel(const float* __restrict__ x) {
    const int n4 = TT * BB * II / 4;
    for (int i = blockIdx.x * blockDim.x + threadIdx.x; i < n4;
         i += gridDim.x * blockDim.x) {
        float4 v = reinterpret_cast<const float4*>(x)[i];
        ushort4 o;
        o.x = f2bf(v.x); o.y = f2bf(v.y); o.z = f2bf(v.z); o.w = f2bf(v.w);
        reinterpret_cast<ushort4*>(g_xbf)[i] = o;
    }
}

// ---------------- phase 1b: wihT [k][n] f32 -> wihB [n][k] bf16 ----------------
__global__ void cvt_wih_kernel(const float* __restrict__ wihT) {
    const int n = blockIdx.x;    // 0..767
    const int k = threadIdx.x;   // 0..255
    g_wihB[n * II + k] = f2bf(wihT[k * NG + n]);
}

// ---------------- phase 2: gi = x @ wihT  (MFMA bf16, fp32 out) ----------------
__global__ void __launch_bounds__(256) gi_gemm_kernel() {
    __shared__ unsigned short Ab[128 * 32];
    __shared__ unsigned short Bb[128 * 32];
    const int tid = threadIdx.x;
    const int mt = blockIdx.x / 6, nt = blockIdx.x % 6;
    const int m0 = mt * 128, n0 = nt * 128;
    const int l = tid & 63, w = tid >> 6;
    const int wr = w >> 1, wc = w & 1;
    const int srow = tid >> 2, scol = (tid & 3) * 8;

    f32x4 acc[4][4] = {};

    for (int ks = 0; ks < 8; ++ks) {
        const int k0 = ks * 32;
        __syncthreads();
        #pragma unroll
        for (int c = 0; c < 2; ++c) {
            const int row = c * 64 + srow;
            *reinterpret_cast<uint4*>(&Ab[row * 32 + scol]) =
                *reinterpret_cast<const uint4*>(&g_xbf[(size_t)(m0 + row) * II + k0 + scol]);
            *reinterpret_cast<uint4*>(&Bb[row * 32 + scol]) =
                *reinterpret_cast<const uint4*>(&g_wihB[(n0 + row) * II + k0 + scol]);
        }
        __syncthreads();
        bfrag af[4], bf[4];
        #pragma unroll
        for (int i = 0; i < 4; ++i) {
            af[i] = *reinterpret_cast<const bfrag*>(
                        &Ab[(wr * 64 + i * 16 + (l & 15)) * 32 + (l >> 4) * 8]);
            bf[i] = *reinterpret_cast<const bfrag*>(
                        &Bb[(wc * 64 + i * 16 + (l & 15)) * 32 + (l >> 4) * 8]);
        }
        #pragma unroll
        for (int mi = 0; mi < 4; ++mi)
            #pragma unroll
            for (int ni = 0; ni < 4; ++ni)
                acc[mi][ni] = __builtin_amdgcn_mfma_f32_16x16x32_bf16(
                                  af[mi], bf[ni], acc[mi][ni], 0, 0, 0);
    }
    #pragma unroll
    for (int mi = 0; mi < 4; ++mi) {
        const int grow = m0 + wr * 64 + mi * 16 + (l >> 4) * 4;
        #pragma unroll
        for (int ni = 0; ni < 4; ++ni) {
            const int gcol = n0 + wc * 64 + ni * 16 + (l & 15);
            #pragma unroll
            for (int q = 0; q < 4; ++q)
                g_gi[(size_t)(grow + q) * NG + gcol] = acc[mi][ni][q];
        }
    }
}

// ---------------- phase 3: recurrence ----------------
// 128 WGs (one per batch row) x 512 threads. Waves 0-3: k in [0,128);
// waves 4-7: k in [128,256). Thread (half, j) holds 64 pairs x 3 gates of
// whh as packed f16x2 in VGPRs (192 words). h ping-pongs in LDS as f16;
// per-wave readlane broadcast (k-half is wave-uniform). gi[t+1] prefetched
// into registers during step t's dot phase.
__global__ void __launch_bounds__(512, 2) gru_rec_kernel(
    const float* __restrict__ h0, const float* __restrict__ whhT,
    const float* __restrict__ bias, float* __restrict__ out)
{
    __shared__ unsigned short hpk[2][HH];   // ping-pong h (f16)
    __shared__ float part[NG];              // half1 partial dots

    const int tid  = threadIdx.x;
    const int half = tid >> 8;              // wave-uniform k-half
    const int j    = tid & 255;             // output column
    const int lane = tid & 63;
    const int b    = blockIdx.x;

    // --- weights into VGPRs (MUST fully unroll: constant indices only) ---
    unsigned wr_[64], wz_[64], wn_[64];
    #pragma unroll
    for (int p = 0; p < 64; ++p) {
        const int k0 = half * 128 + 2 * p;
        const float r0 = whhT[(size_t)k0 * NG + j];
        const float r1 = whhT[(size_t)(k0 + 1) * NG + j];
        const float z0 = whhT[(size_t)k0 * NG + 256 + j];
        const float z1 = whhT[(size_t)(k0 + 1) * NG + 256 + j];
        const float n0 = whhT[(size_t)k0 * NG + 512 + j];
        const float n1 = whhT[(size_t)(k0 + 1) * NG + 512 + j];
        wr_[p] = pk2(r0, r1);
        wz_[p] = pk2(z0, z1);
        wn_[p] = pk2(n0, n1);
    }

    const float br = bias[j], bz = bias[256 + j], bn = bias[512 + j];

    float hprev = 0.f;
    if (half == 0) {
        hprev = h0[b * HH + j];
        hpk[0][j] = f2h_bits(hprev);
    }
    __syncthreads();

    const float* gib = g_gi + (size_t)b * NG + j;
    float giR = 0.f, giZ = 0.f, giN = 0.f;
    if (half == 0) { giR = gib[0]; giZ = gib[256]; giN = gib[512]; }

    for (int t = 0; t < TT; ++t) {
        // prefetch gi[t+1] (registers); consumed next iteration
        float nR = 0.f, nZ = 0.f, nN = 0.f;
        if (half == 0 && t + 1 < TT) {
            const float* gt1 = gib + (size_t)(t + 1) * (BB * NG);
            nR = gt1[0]; nZ = gt1[256]; nN = gt1[512];
        }

        const unsigned* hp32 =
            reinterpret_cast<const unsigned*>(&hpk[t & 1][0]);
        const unsigned src = hp32[half * 64 + lane];   // wave holds 64 pairs

        // 6 accumulator chains for ILP
        float aR = 0.f, aZ = 0.f, aN = 0.f, cR = 0.f, cZ = 0.f, cN = 0.f;
        #pragma unroll
        for (int p = 0; p < 64; ++p) {
            const unsigned hu =
                (unsigned)__builtin_amdgcn_readlane((int)src, p);
            const h2t hh = __builtin_bit_cast(h2t, hu);
            if ((p & 1) == 0) {
                aR = __builtin_amdgcn_fdot2(hh, __builtin_bit_cast(h2t, wr_[p]), aR, false);
                aZ = __builtin_amdgcn_fdot2(hh, __builtin_bit_cast(h2t, wz_[p]), aZ, false);
                aN = __builtin_amdgcn_fdot2(hh, __builtin_bit_cast(h2t, wn_[p]), aN, false);
            } else {
                cR = __builtin_amdgcn_fdot2(hh, __builtin_bit_cast(h2t, wr_[p]), cR, false);
                cZ = __builtin_amdgcn_fdot2(hh, __builtin_bit_cast(h2t, wz_[p]), cZ, false);
                cN = __builtin_amdgcn_fdot2(hh, __builtin_bit_cast(h2t, wn_[p]), cN, false);
            }
        }
        const float accR = aR + cR, accZ = aZ + cZ, accN = aN + cN;

        if (half == 1) {
            part[j]       = accR;
            part[256 + j] = accZ;
            part[512 + j] = accN;
        }
        __syncthreads();
        if (half == 0) {
            const float sR = accR + part[j];
            const float sZ = accZ + part[256 + j];
            const float sN = accN + part[512 + j];
            const float r = 1.f / (1.f + __expf(-(giR + br + sR)));
            const float z = 1.f / (1.f + __expf(-(giZ + bz + sZ)));
            const float e = __expf(2.f * (giN + bn + r * sN));   // tanh
            const float n = 1.f - 2.f / (e + 1.f);
            const float hn = (1.f - z) * n + z * hprev;
            hprev = hn;
            hpk[(t & 1) ^ 1][j] = f2h_bits(hn);
            if (t == TT - 1) out[b * HH + j] = hn;
            giR = nR; giZ = nZ; giN = nN;
        }
        __syncthreads();
    }
}

extern "C" void kernel_launch(void* const* d_in, const int* in_sizes, int n_in,
                              void* d_out, int out_size, void* d_ws, size_t ws_size,
                              hipStream_t stream) {
    const float* x    = (const float*)d_in[0];
    const float* h0   = (const float*)d_in[1];
    const float* wihT = (const float*)d_in[2];
    const float* whhT = (const float*)d_in[3];
    const float* bias = (const float*)d_in[4];
    float*       out  = (float*)d_out;

    cvt_x_kernel<<<2048, 256, 0, stream>>>(x);
    cvt_wih_kernel<<<NG, 256, 0, stream>>>(wihT);
    gi_gemm_kernel<<<1024 * 6, 256, 0, stream>>>();
    gru_rec_kernel<<<BB, 512, 0, stream>>>(h0, whhT, bias, out);
}